// Round 6
// baseline (332.059 us; speedup 1.0000x reference)
//
#include <hip/hip_runtime.h>

#define N_NODES 50000
#define N_EDGES 800000
#define NFEAT   512
#define NHID    256
#define NCLASS  64

#define MTILES     ((N_NODES + 63) / 64)      // 782

// ---- bucketed CSR build params ----
#define NBUCK      196                        // ceil(50000/256), bucket = dst>>8
#define BCAP       5632                       // expected 4096 +- 64; +24 sigma margin
#define BIN_CHUNK  4096
#define BIN_BLOCKS ((N_EDGES + BIN_CHUNK - 1) / BIN_CHUNK)   // 196 per list
#define PREP_BLOCKS (2 * BIN_BLOCKS + 32 + 4)                // binscatter + casts
#define FUSE_BLOCKS (2 * NBUCK + MTILES)                     // bucket_csr + gemm1

typedef short short8  __attribute__((ext_vector_type(8)));
typedef float floatx4 __attribute__((ext_vector_type(4)));
typedef float floatx2 __attribute__((ext_vector_type(2)));

__device__ inline short f2bf(float f) {
    unsigned u = __builtin_bit_cast(unsigned, f);
    u += 0x7FFF + ((u >> 16) & 1);   // round-to-nearest-even
    return (short)(u >> 16);
}
__device__ inline float bf2f(short v) {
    unsigned u = ((unsigned)(unsigned short)v) << 16;
    return __builtin_bit_cast(float, u);
}
// packed edge: low 16 bits = src node id (50000 < 65536), high 16 = bf16 weight
__device__ inline int pack_edge(int src, float w) {
    return (src & 0xFFFF) | ((int)(unsigned short)f2bf(w) << 16);
}

// ---- fp8 e4m3fn (OCP) helpers: HW cvt on gfx950, bit-manip fallback ----
#if defined(__has_builtin)
#if __has_builtin(__builtin_amdgcn_cvt_pk_f32_fp8) && __has_builtin(__builtin_amdgcn_cvt_pk_fp8_f32)
#define HAVE_HW_FP8 1
#endif
#endif

__device__ inline unsigned char f2fp8(float f) {
#ifdef HAVE_HW_FP8
    return (unsigned char)(__builtin_amdgcn_cvt_pk_fp8_f32(f, f, 0, false) & 0xFF);
#else
    unsigned u = __builtin_bit_cast(unsigned, f);
    unsigned s = (u >> 31) << 7;
    float af = fabsf(f);
    if (!(af >= 0.0009765625f)) {
        int q = (int)(af * 512.f + 0.5f);
        if (q > 7) q = 7;
        return (unsigned char)(s | q);
    }
    if (af > 448.f) return (unsigned char)(s | 0x7E);
    int ex; float mf = frexpf(af, &ex);
    int E = ex - 1;
    if (E < -6) {
        int q = (int)(af * 512.f + 0.5f);
        if (q > 7) q = 7;
        return (unsigned char)(s | q);
    }
    int m = (int)((2.f * mf - 1.f) * 8.f + 0.5f);
    if (m == 8) { m = 0; ++E; }
    if (E > 8) return (unsigned char)(s | 0x7E);
    return (unsigned char)(s | ((E + 7) << 3) | m);
#endif
}

__device__ inline void fp8x8_to_f32(uint2 v, float* o) {
#ifdef HAVE_HW_FP8
    floatx2 f0 = __builtin_amdgcn_cvt_pk_f32_fp8((int)v.x, false);
    floatx2 f1 = __builtin_amdgcn_cvt_pk_f32_fp8((int)v.x, true);
    floatx2 f2 = __builtin_amdgcn_cvt_pk_f32_fp8((int)v.y, false);
    floatx2 f3 = __builtin_amdgcn_cvt_pk_f32_fp8((int)v.y, true);
    o[0] = f0[0]; o[1] = f0[1]; o[2] = f1[0]; o[3] = f1[1];
    o[4] = f2[0]; o[5] = f2[1]; o[6] = f3[0]; o[7] = f3[1];
#else
    unsigned w[2] = {v.x, v.y};
    #pragma unroll
    for (int k = 0; k < 8; ++k) {
        unsigned char b = (w[k >> 2] >> ((k & 3) * 8)) & 0xFF;
        int sg = b >> 7, e = (b >> 3) & 15, m = b & 7;
        float val = e ? ldexpf(1.f + m * 0.125f, e - 7) : ldexpf(m * 0.125f, -6);
        o[k] = sg ? -val : val;
    }
#endif
}

// async global->LDS 16B: linear LDS dest (base + lane*16), per-lane global src
typedef __attribute__((address_space(3))) void       lds_void;
typedef __attribute__((address_space(1))) const void glb_void;
__device__ inline void gload_lds16(const void* g, void* l) {
    __builtin_amdgcn_global_load_lds((glb_void*)g, (lds_void*)l, 16, 0, 0);
}

// ---------------- prep: binscatter (both lists) + both weight casts, one dispatch ----
__global__ __launch_bounds__(256) void prep_kernel(
    const int* __restrict__ es0, const int* __restrict__ ed0, const float* __restrict__ ew0,
    int* __restrict__ cur0, int2* __restrict__ bin0,
    const int* __restrict__ es1, const int* __restrict__ ed1, const float* __restrict__ ew1,
    int* __restrict__ cur1, int2* __restrict__ bin1,
    const float* __restrict__ W1, short* __restrict__ Wt,
    const float* __restrict__ W2, short* __restrict__ W2t) {
    __shared__ union {
        int   hist[NBUCK];
        short tile[64][72];
    } sm;
    const int blk = blockIdx.x;
    const int t   = threadIdx.x;

    if (blk < 2 * BIN_BLOCKS) {
        // ---- binscatter ----
        const int list = blk >= BIN_BLOCKS;
        const int cb   = blk - list * BIN_BLOCKS;
        const int*   es  = list ? es1 : es0;
        const int*   ed  = list ? ed1 : ed0;
        const float* ew  = list ? ew1 : ew0;
        int*         cur = list ? cur1 : cur0;
        int2*        bin = list ? bin1 : bin0;

        const int e0 = cb * BIN_CHUNK;
        const int e1 = min(e0 + BIN_CHUNK, N_EDGES);

        if (t < NBUCK) sm.hist[t] = 0;
        __syncthreads();
        for (int e = e0 + t; e < e1; e += 256)
            atomicAdd(&sm.hist[ed[e] >> 8], 1);
        __syncthreads();
        if (t < NBUCK) sm.hist[t] = atomicAdd(&cur[t], sm.hist[t]);
        __syncthreads();
        for (int e = e0 + t; e < e1; e += 256) {
            int d = ed[e];
            int b = d >> 8;
            int p = atomicAdd(&sm.hist[b], 1);
            if (p < BCAP) {
                int2 v; v.x = pack_edge(es[e], ew[e]); v.y = d;
                bin[(size_t)b * BCAP + p] = v;
            }
        }
    } else if (blk < 2 * BIN_BLOCKS + 32) {
        // ---- cast W1 -> Wt [256x512] bf16 (transposed) ----
        const int cb = blk - 2 * BIN_BLOCKS;
        const int k0 = (cb >> 2) << 6;
        const int n0 = (cb & 3) << 6;
        {
            int kr = t >> 2, ng = (t & 3) << 4;
            const float* src = W1 + (size_t)(k0 + kr) * NHID + n0 + ng;
            float4 v0 = ((const float4*)src)[0], v1 = ((const float4*)src)[1];
            float4 v2 = ((const float4*)src)[2], v3 = ((const float4*)src)[3];
            short* d = &sm.tile[kr][ng];
            d[0]=f2bf(v0.x); d[1]=f2bf(v0.y); d[2]=f2bf(v0.z); d[3]=f2bf(v0.w);
            d[4]=f2bf(v1.x); d[5]=f2bf(v1.y); d[6]=f2bf(v1.z); d[7]=f2bf(v1.w);
            d[8]=f2bf(v2.x); d[9]=f2bf(v2.y); d[10]=f2bf(v2.z); d[11]=f2bf(v2.w);
            d[12]=f2bf(v3.x); d[13]=f2bf(v3.y); d[14]=f2bf(v3.z); d[15]=f2bf(v3.w);
        }
        __syncthreads();
        {
            int nr = t >> 2, kg = (t & 3) << 4;
            short8 o0, o1;
            #pragma unroll
            for (int j = 0; j < 8; ++j) { o0[j] = sm.tile[kg + j][nr]; o1[j] = sm.tile[kg + 8 + j][nr]; }
            short* d = Wt + (size_t)(n0 + nr) * NFEAT + k0 + kg;
            *(short8*)d = o0;
            *(short8*)(d + 8) = o1;
        }
    } else {
        // ---- cast W2 -> W2t [64x256] bf16 (transposed) ----
        const int cb = blk - 2 * BIN_BLOCKS - 32;
        const int k0 = cb << 6;
        {
            int kr = t >> 2, ng = (t & 3) << 4;
            const float* src = W2 + (size_t)(k0 + kr) * NCLASS + ng;
            float4 v0 = ((const float4*)src)[0], v1 = ((const float4*)src)[1];
            float4 v2 = ((const float4*)src)[2], v3 = ((const float4*)src)[3];
            short* d = &sm.tile[kr][ng];
            d[0]=f2bf(v0.x); d[1]=f2bf(v0.y); d[2]=f2bf(v0.z); d[3]=f2bf(v0.w);
            d[4]=f2bf(v1.x); d[5]=f2bf(v1.y); d[6]=f2bf(v1.z); d[7]=f2bf(v1.w);
            d[8]=f2bf(v2.x); d[9]=f2bf(v2.y); d[10]=f2bf(v2.z); d[11]=f2bf(v2.w);
            d[12]=f2bf(v3.x); d[13]=f2bf(v3.y); d[14]=f2bf(v3.z); d[15]=f2bf(v3.w);
        }
        __syncthreads();
        {
            int nr = t >> 2, kg = (t & 3) << 4;
            short8 o0, o1;
            #pragma unroll
            for (int j = 0; j < 8; ++j) { o0[j] = sm.tile[kg + j][nr]; o1[j] = sm.tile[kg + 8 + j][nr]; }
            short* d = W2t + (size_t)nr * NHID + k0 + kg;
            *(short8*)d = o0;
            *(short8*)(d + 8) = o1;
        }
    }
}

// ------- FUSED: bucket_csr (blocks [0,392)) + gemm1 (blocks [392,392+782)) ---------
// The two phases are mutually independent (csr needs bin/cur, gemm1 needs Wt/x);
// fusing overlaps csr's latency-bound LDS/atomic work with gemm1's MFMA/BW work
// (separate pipes co-schedule, m114) and removes one launch gap.
__global__ __launch_bounds__(256) void csr_gemm1_kernel(
    const int* __restrict__ cur0, const int2* __restrict__ bin0,
    int* __restrict__ deg0, int* __restrict__ base0, int* __restrict__ edge0,
    const int* __restrict__ cur1, const int2* __restrict__ bin1,
    int* __restrict__ deg1, int* __restrict__ base1, int* __restrict__ edge1,
    const float* __restrict__ x, const short* __restrict__ Wt,
    unsigned char* __restrict__ h0f) {
    __shared__ union {
        struct { short As[2][64 * 64]; short Bs[2][256 * 64]; } g;   // 80 KB (gemm1)
        struct { int dh[256]; int sc[256]; int pc[256]; } c;         // 3 KB  (csr)
    } sm;
    const int tid = threadIdx.x;

    if (blockIdx.x < 2 * NBUCK) {
        // ================= bucket_csr (inlined 196-bucket prefix scan) =============
        const int list = blockIdx.x >= NBUCK;
        const int b    = blockIdx.x - list * NBUCK;
        const int*  cur  = list ? cur1  : cur0;
        const int2* bin  = (list ? bin1 : bin0) + (size_t)b * BCAP;
        int*        deg  = list ? deg1  : deg0;
        int*        base = list ? base1 : base0;
        int*        edge = list ? edge1 : edge0;
        const int t = tid;

        sm.c.pc[t] = (t < NBUCK) ? min(cur[t], BCAP) : 0;
        sm.c.dh[t] = 0;
        __syncthreads();
        for (int off = 1; off < 256; off <<= 1) {
            int a = (t >= off) ? sm.c.pc[t - off] : 0;
            __syncthreads();
            sm.c.pc[t] += a;
            __syncthreads();
        }
        const int gbase = b ? sm.c.pc[b - 1] : 0;
        const int len   = min(cur[b], BCAP);
        const int n0    = b << 8;

        for (int i = t; i < len; i += 256)
            atomicAdd(&sm.c.dh[bin[i].y & 255], 1);
        __syncthreads();
        int v = sm.c.dh[t];
        sm.c.sc[t] = v;
        __syncthreads();
        for (int off = 1; off < 256; off <<= 1) {
            int a = (t >= off) ? sm.c.sc[t - off] : 0;
            __syncthreads();
            sm.c.sc[t] += a;
            __syncthreads();
        }
        int excl = sm.c.sc[t] - v;
        int node = n0 + t;
        if (node < N_NODES) { deg[node] = v; base[node] = gbase + excl; }
        sm.c.dh[t] = gbase + excl;
        __syncthreads();
        for (int i = t; i < len; i += 256) {
            int2 ev = bin[i];
            int p = atomicAdd(&sm.c.dh[ev.y & 255], 1);
            edge[p] = ev.x;
        }
        return;
    }

    // ================= gemm1: h0 = fp8(x @ W1), BK=64, swizzled LDS, 2-ph dbuf =====
    const int tile = blockIdx.x - 2 * NBUCK;
    const int wave = tid >> 6, lane = tid & 63;
    const int mlo  = lane & 15, q = lane >> 4;
    const int m0   = tile * 64;

    const int ar = tid >> 2;
    const int cp = (tid & 3) * 2;
    int arow = m0 + ar; if (arow >= N_NODES) arow = N_NODES - 1;
    const float* aptr = x + (size_t)arow * NFEAT + cp * 8;

    const int brl = lane >> 3;
    const int bsl = lane & 7;

    floatx4 acc[4][4] = {};

    // prologue: stage tile 0 into buffer 0
    #pragma unroll
    for (int i = 0; i < 8; ++i) {
        int r  = wave * 64 + i * 8 + brl;
        int s2 = bsl ^ (r & 7);
        gload_lds16(Wt + (size_t)r * NFEAT + s2 * 8, &sm.g.Bs[0][(wave * 64 + i * 8) * 64]);
    }
    {
        float4 a0 = *(const float4*)(aptr);
        float4 a1 = *(const float4*)(aptr + 4);
        float4 a2 = *(const float4*)(aptr + 8);
        float4 a3 = *(const float4*)(aptr + 12);
        short8 p0, p1;
        p0[0]=f2bf(a0.x); p0[1]=f2bf(a0.y); p0[2]=f2bf(a0.z); p0[3]=f2bf(a0.w);
        p0[4]=f2bf(a1.x); p0[5]=f2bf(a1.y); p0[6]=f2bf(a1.z); p0[7]=f2bf(a1.w);
        p1[0]=f2bf(a2.x); p1[1]=f2bf(a2.y); p1[2]=f2bf(a2.z); p1[3]=f2bf(a2.w);
        p1[4]=f2bf(a3.x); p1[5]=f2bf(a3.y); p1[6]=f2bf(a3.z); p1[7]=f2bf(a3.w);
        *(short8*)&sm.g.As[0][ar * 64 + ((cp     ) ^ (ar & 7)) * 8] = p0;
        *(short8*)&sm.g.As[0][ar * 64 + ((cp + 1) ^ (ar & 7)) * 8] = p1;
    }
    __syncthreads();

    int pb = 0;
    for (int kc = 0; kc < NFEAT; kc += 64) {
        const int nxt = kc + 64;
        float4 a0, a1, a2, a3;
        if (nxt < NFEAT) {
            // issue next-tile stages first (loads fly during MFMA below)
            #pragma unroll
            for (int i = 0; i < 8; ++i) {
                int r  = wave * 64 + i * 8 + brl;
                int s2 = bsl ^ (r & 7);
                gload_lds16(Wt + (size_t)r * NFEAT + nxt + s2 * 8,
                            &sm.g.Bs[pb ^ 1][(wave * 64 + i * 8) * 64]);
            }
            a0 = *(const float4*)(aptr + nxt);
            a1 = *(const float4*)(aptr + nxt + 4);
            a2 = *(const float4*)(aptr + nxt + 8);
            a3 = *(const float4*)(aptr + nxt + 12);
        }
        // compute tile kc from buffer pb
        #pragma unroll
        for (int h = 0; h < 2; ++h) {
            short8 afv[4], bfv[4];
            #pragma unroll
            for (int t2 = 0; t2 < 4; ++t2) {
                int r = t2 * 16 + mlo;
                afv[t2] = *(const short8*)&sm.g.As[pb][r * 64 + ((h * 4 + q) ^ (r & 7)) * 8];
            }
            #pragma unroll
            for (int u = 0; u < 4; ++u) {
                int r = wave * 64 + u * 16 + mlo;
                bfv[u] = *(const short8*)&sm.g.Bs[pb][r * 64 + ((h * 4 + q) ^ (r & 7)) * 8];
            }
            #pragma unroll
            for (int t2 = 0; t2 < 4; ++t2)
                #pragma unroll
                for (int u = 0; u < 4; ++u)
                    acc[t2][u] = __builtin_amdgcn_mfma_f32_16x16x32_bf16(afv[t2], bfv[u], acc[t2][u], 0, 0, 0);
        }
        if (nxt < NFEAT) {
            short8 p0, p1;
            p0[0]=f2bf(a0.x); p0[1]=f2bf(a0.y); p0[2]=f2bf(a0.z); p0[3]=f2bf(a0.w);
            p0[4]=f2bf(a1.x); p0[5]=f2bf(a1.y); p0[6]=f2bf(a1.z); p0[7]=f2bf(a1.w);
            p1[0]=f2bf(a2.x); p1[1]=f2bf(a2.y); p1[2]=f2bf(a2.z); p1[3]=f2bf(a2.w);
            p1[4]=f2bf(a3.x); p1[5]=f2bf(a3.y); p1[6]=f2bf(a3.z); p1[7]=f2bf(a3.w);
            *(short8*)&sm.g.As[pb ^ 1][ar * 64 + ((cp     ) ^ (ar & 7)) * 8] = p0;
            *(short8*)&sm.g.As[pb ^ 1][ar * 64 + ((cp + 1) ^ (ar & 7)) * 8] = p1;
        }
        __syncthreads();
        pb ^= 1;
    }

    #pragma unroll
    for (int t2 = 0; t2 < 4; ++t2) {
        #pragma unroll
        for (int r = 0; r < 4; ++r) {
            int row = m0 + t2 * 16 + q * 4 + r;
            if (row < N_NODES) {
                #pragma unroll
                for (int u = 0; u < 4; ++u)
                    h0f[(size_t)row * NHID + wave * 64 + u * 16 + mlo] = f2fp8(acc[t2][u][r]);
            }
        }
    }
}

// ---------------- SpMM1 pull (fp8, d=256): XCD feature-split, 4 slots, depth-3 ------
__global__ __launch_bounds__(256) void spmm1_pull_kernel(const int* __restrict__ base,
                                                         const int* __restrict__ deg,
                                                         const int* __restrict__ edge_s,
                                                         const unsigned char* __restrict__ h0f,
                                                         short* __restrict__ agg0b) {
    const int g    = blockIdx.x;
    const int r7   = g & 7;
    const int half = r7 >> 2;                       // 0/1 feature half
    const int nb   = (g >> 3) * 4 + (r7 & 3);       // node-block 0..12499
    const int node = nb * 4 + (threadIdx.x >> 6);
    const int lane = threadIdx.x & 63;
    const int slot = lane >> 4;                     // 4 slots, stride 4
    const int c    = lane & 15;
    const int fof  = half * 128 + c * 8;            // feature offset (fp8: 1 B/elem)
    const int start = base[node];
    const int len   = deg[node];

    float acc[8] = {0.f,0.f,0.f,0.f,0.f,0.f,0.f,0.f};

    int eA = 0, eB = 0, eC = 0, eD = 0;
    uint2 z = {0u, 0u};
    uint2 hA = z, hB = z, hC = z;
    if (slot      < len) eA = edge_s[start + slot];
    if (slot + 4  < len) eB = edge_s[start + slot + 4];
    if (slot + 8  < len) eC = edge_s[start + slot + 8];
    if (slot + 12 < len) eD = edge_s[start + slot + 12];
    if (slot      < len) hA = *(const uint2*)(h0f + (size_t)(eA & 0xFFFF) * NHID + fof);
    if (slot + 4  < len) hB = *(const uint2*)(h0f + (size_t)(eB & 0xFFFF) * NHID + fof);
    if (slot + 8  < len) hC = *(const uint2*)(h0f + (size_t)(eC & 0xFFFF) * NHID + fof);

    int jr = slot + 12;   // next row index to issue
    int je = slot + 16;   // next edge index to fetch
    for (int j = slot; j < len; j += 4) {
        float wt = bf2f((short)((unsigned)eA >> 16));
        float f[8];
        fp8x8_to_f32(hA, f);
        #pragma unroll
        for (int k = 0; k < 8; ++k) acc[k] += wt * f[k];
        eA = eB; hA = hB;
        eB = eC; hB = hC;
        eC = eD;
        if (jr < len) hC = *(const uint2*)(h0f + (size_t)(eC & 0xFFFF) * NHID + fof);
        if (je < len) eD = edge_s[start + je];
        jr += 4; je += 4;
    }

    #pragma unroll
    for (int k = 0; k < 8; ++k) {
        acc[k] += __shfl_xor(acc[k], 16);
        acc[k] += __shfl_xor(acc[k], 32);
    }
    if (slot == 0) {
        short8 ob;
        #pragma unroll
        for (int k = 0; k < 8; ++k) ob[k] = f2bf(acc[k]);
        *(short8*)(agg0b + (size_t)node * NHID + fof) = ob;
    }
}

// ---------------- GEMM2: h2 = bf16(relu(agg0b + b1) @ W2), BK=64, swizzled LDS ------
__global__ __launch_bounds__(256) void gemm2_mfma_kernel(const short* __restrict__ agg0b,
                                                         const float* __restrict__ b1,
                                                         const short* __restrict__ W2t,
                                                         short* __restrict__ h2b) {
    __shared__ short Bs[64 * 256];   // 32 KB [n][k=256] swizzled (chunk ^= row&7)
    __shared__ short As[64 * 64];    // 8 KB  [m][k] swizzled
    const int tid  = threadIdx.x;
    const int wave = tid >> 6, lane = tid & 63;
    const int mlo  = lane & 15, q = lane >> 4;
    const int m0   = blockIdx.x * 64;

    {   // stage full W2t [64x256] once, swizzled
        int n = tid >> 2;
        #pragma unroll
        for (int j = 0; j < 8; ++j) {
            int c  = (tid & 3) * 8 + j;              // chunk 0..31
            int s2 = c ^ (n & 7);
            *(short8*)&Bs[n * 256 + s2 * 8] =
                *(const short8*)(W2t + (size_t)n * NHID + c * 8);
        }
    }

    const int ar = tid >> 2;
    const int cp = (tid & 3) * 2;
    int arow = m0 + ar; if (arow >= N_NODES) arow = N_NODES - 1;
    const short* aptr = agg0b + (size_t)arow * NHID + cp * 8;

    floatx4 acc[4] = {};   // [ntile]

    for (int kc = 0; kc < NHID; kc += 64) {
        short8 s0 = *(const short8*)(aptr + kc);
        short8 s1 = *(const short8*)(aptr + kc + 8);
        float4 c0 = *(const float4*)(b1 + kc + cp * 8);
        float4 c1 = *(const float4*)(b1 + kc + cp * 8 + 4);
        float4 c2 = *(const float4*)(b1 + kc + cp * 8 + 8);
        float4 c3 = *(const float4*)(b1 + kc + cp * 8 + 12);
        float v0 = bf2f(s0[0]) + c0.x, v1 = bf2f(s0[1]) + c0.y;
        float v2 = bf2f(s0[2]) + c0.z, v3 = bf2f(s0[3]) + c0.w;
        float v4 = bf2f(s0[4]) + c1.x, v5 = bf2f(s0[5]) + c1.y;
        float v6 = bf2f(s0[6]) + c1.z, v7 = bf2f(s0[7]) + c1.w;
        float v8 = bf2f(s1[0]) + c2.x, v9 = bf2f(s1[1]) + c2.y;
        float vA = bf2f(s1[2]) + c2.z, vB = bf2f(s1[3]) + c2.w;
        float vC = bf2f(s1[4]) + c3.x, vD = bf2f(s1[5]) + c3.y;
        float vE = bf2f(s1[6]) + c3.z, vF = bf2f(s1[7]) + c3.w;
        short8 p0, p1;
        p0[0]=f2bf(v0>0.f?v0:0.f); p0[1]=f2bf(v1>0.f?v1:0.f); p0[2]=f2bf(v2>0.f?v2:0.f); p0[3]=f2bf(v3>0.f?v3:0.f);
        p0[4]=f2bf(v4>0.f?v4:0.f); p0[5]=f2bf(v5>0.f?v5:0.f); p0[6]=f2bf(v6>0.f?v6:0.f); p0[7]=f2bf(v7>0.f?v7:0.f);
        p1[0]=f2bf(v8>0.f?v8:0.f); p1[1]=f2bf(v9>0.f?v9:0.f); p1[2]=f2bf(vA>0.f?vA:0.f); p1[3]=f2bf(vB>0.f?vB:0.f);
        p1[4]=f2bf(vC>0.f?vC:0.f); p1[5]=f2bf(vD>0.f?vD:0.f); p1[6]=f2bf(vE>0.f?vE:0.f); p1[7]=f2bf(vF>0.f?vF:0.f);
        *(short8*)&As[ar * 64 + ((cp     ) ^ (ar & 7)) * 8] = p0;
        *(short8*)&As[ar * 64 + ((cp + 1) ^ (ar & 7)) * 8] = p1;
        __syncthreads();

        short8 afv[2];
        {
            int r = wave * 16 + mlo;
            afv[0] = *(const short8*)&As[r * 64 + ((    q) ^ (r & 7)) * 8];
            afv[1] = *(const short8*)&As[r * 64 + ((4 + q) ^ (r & 7)) * 8];
        }
        #pragma unroll
        for (int u = 0; u < 4; ++u) {
            int r = u * 16 + mlo;
            #pragma unroll
            for (int h = 0; h < 2; ++h) {
                int ch = (kc >> 3) + h * 4 + q;
                short8 bv = *(const short8*)&Bs[r * 256 + (ch ^ (r & 7)) * 8];
                acc[u] = __builtin_amdgcn_mfma_f32_16x16x32_bf16(afv[h], bv, acc[u], 0, 0, 0);
            }
        }
        __syncthreads();
    }

    #pragma unroll
    for (int r = 0; r < 4; ++r) {
        int row = m0 + wave * 16 + q * 4 + r;
        if (row < N_NODES) {
            #pragma unroll
            for (int u = 0; u < 4; ++u)
                h2b[(size_t)row * NCLASS + u * 16 + mlo] = f2bf(acc[u][r]);
        }
    }
}

// ---------------- Fused SpMM2 + bias + log_softmax (d=64) ----------------
__global__ __launch_bounds__(256) void spmm2_lsm_kernel(const int* __restrict__ base,
                                                        const int* __restrict__ deg,
                                                        const int* __restrict__ edge_s,
                                                        const short* __restrict__ h2b,
                                                        const float* __restrict__ b2,
                                                        float* __restrict__ out) {
    const int node = blockIdx.x * 4 + (threadIdx.x >> 6);
    const int lane = threadIdx.x & 63;
    const int slot = lane >> 3;
    const int f    = lane & 7;          // feats f*8..f*8+7
    const int start = base[node];
    const int len   = deg[node];

    float acc[8] = {0.f,0.f,0.f,0.f,0.f,0.f,0.f,0.f};
    int j = slot;
    int e = 0;
    short8 hv = {0,0,0,0,0,0,0,0};
    if (j < len) {
        e  = edge_s[start + j];
        hv = *(const short8*)(h2b + (size_t)(e & 0xFFFF) * NCLASS + f * 8);
    }
    while (j < len) {
        float wt = bf2f((short)((unsigned)e >> 16));
        int jn = j + 8;
        int en = e; short8 hn = hv;
        if (jn < len) {
            en = edge_s[start + jn];
            hn = *(const short8*)(h2b + (size_t)(en & 0xFFFF) * NCLASS + f * 8);
        }
        #pragma unroll
        for (int k = 0; k < 8; ++k) acc[k] += wt * bf2f(hv[k]);
        e = en; hv = hn; j = jn;
    }
    #pragma unroll
    for (int k = 0; k < 8; ++k) {
        acc[k] += __shfl_xor(acc[k], 8);
        acc[k] += __shfl_xor(acc[k], 16);
        acc[k] += __shfl_xor(acc[k], 32);
    }
    float4 c0 = *(const float4*)(b2 + f * 8);
    float4 c1 = *(const float4*)(b2 + f * 8 + 4);
    float v[8];
    v[0] = acc[0] + c0.x; v[1] = acc[1] + c0.y; v[2] = acc[2] + c0.z; v[3] = acc[3] + c0.w;
    v[4] = acc[4] + c1.x; v[5] = acc[5] + c1.y; v[6] = acc[6] + c1.z; v[7] = acc[7] + c1.w;
    float m = v[0];
    #pragma unroll
    for (int k = 1; k < 8; ++k) m = fmaxf(m, v[k]);
    m = fmaxf(m, __shfl_xor(m, 1));
    m = fmaxf(m, __shfl_xor(m, 2));
    m = fmaxf(m, __shfl_xor(m, 4));
    float s = 0.f;
    #pragma unroll
    for (int k = 0; k < 8; ++k) s += __expf(v[k] - m);
    s += __shfl_xor(s, 1);
    s += __shfl_xor(s, 2);
    s += __shfl_xor(s, 4);
    float ls = m + __logf(s);
    if (slot == 0) {
        float4 o0 = {v[0] - ls, v[1] - ls, v[2] - ls, v[3] - ls};
        float4 o1 = {v[4] - ls, v[5] - ls, v[6] - ls, v[7] - ls};
        float* p = out + (size_t)node * NCLASS + f * 8;
        *(float4*)p = o0;
        *(float4*)(p + 4) = o1;
    }
}

extern "C" void kernel_launch(void* const* d_in, const int* in_sizes, int n_in,
                              void* d_out, int out_size, void* d_ws, size_t ws_size,
                              hipStream_t stream) {
    const float* x   = (const float*)d_in[0];
    const int*   es0 = (const int*)  d_in[1];
    const int*   ed0 = (const int*)  d_in[2];
    const float* ew0 = (const float*)d_in[3];
    const int*   es1 = (const int*)  d_in[4];
    const int*   ed1 = (const int*)  d_in[5];
    const float* ew1 = (const float*)d_in[6];
    const float* W1  = (const float*)d_in[7];
    const float* b1  = (const float*)d_in[8];
    const float* W2  = (const float*)d_in[9];
    const float* b2  = (const float*)d_in[10];
    float* out = (float*)d_out;

    // ws layout:
    //   [0, 12.8MB):      h0f fp8 [50000x256]; later h2b bf16 [50000x64] at [0,6.4)
    //   [25.6, 43.3MB):   bin0, bin1 (196 buckets x 5632 x 8B each)  [build-only]
    //   [44.0, 47.7MB):   CSR1 (deg1/base1/edge1) + bucket cursors
    //   [51.2, 76.8MB):   agg0b bf16 [50000x256]
    char* ws = (char*)d_ws;
    const size_t SZ_H0 = (size_t)N_NODES * NHID * sizeof(short);     // 25.6 MB (layout anchor)
    const size_t SZ_BIN = (size_t)NBUCK * BCAP * sizeof(int2);       // 8.83 MB
    unsigned char* h0f = (unsigned char*)ws;
    short* h2b   = (short*)ws;
    short* agg0b = (short*)(ws + (size_t)N_NODES * NHID * sizeof(float));   // 51.2MB

    int2* bin0 = (int2*)(ws + SZ_H0);
    int2* bin1 = (int2*)(ws + SZ_H0 + SZ_BIN);

    char* c1 = ws + 44000000;
    int* deg1  = (int*)c1;
    int* base1 = deg1 + N_NODES;
    int* edge1 = base1 + N_NODES;
    int* cur0  = edge1 + N_EDGES;
    int* cur1  = cur0 + 256;

    // d_out scratch (12.8 MB; CSR0 dead after spmm1; Wt/W2t dead after gemms;
    // final fused spmm2+logsoftmax overwrites all of d_out):
    int*   deg0  = (int*)d_out;
    int*   base0 = deg0 + N_NODES;
    int*   edge0 = base0 + N_NODES;
    short* Wt    = (short*)((char*)d_out + (8u << 20));
    short* W2t   = (short*)((char*)d_out + (9u << 20));

    // ---- build both CSRs + weight casts (fused prep) ----
    hipMemsetAsync(cur0, 0, 512 * sizeof(int), stream);   // cur0 + cur1
    prep_kernel<<<PREP_BLOCKS, 256, 0, stream>>>(es0, ed0, ew0, cur0, bin0,
                                                 es1, ed1, ew1, cur1, bin1,
                                                 W1, Wt, W2, W2t);

    // ---- fused: CSR finalize (independent) + layer-1 GEMM ----
    csr_gemm1_kernel<<<FUSE_BLOCKS, 256, 0, stream>>>(cur0, bin0, deg0, base0, edge0,
                                                      cur1, bin1, deg1, base1, edge1,
                                                      x, Wt, h0f);

    // ---- layer 1 aggregation ----
    spmm1_pull_kernel<<<2 * (N_NODES / 4), 256, 0, stream>>>(base0, deg0, edge0, h0f, agg0b);

    // ---- layer 2 (spmm2 fused with bias + log_softmax, writes out directly) ----
    gemm2_mfma_kernel<<<MTILES, 256, 0, stream>>>(agg0b, b1, W2t, h2b);
    spmm2_lsm_kernel<<<N_NODES / 4, 256, 0, stream>>>(base1, deg1, edge1, h2b, b2, out);
}

// Round 7
// 327.067 us; speedup vs baseline: 1.0153x; 1.0153x over previous
//
#include <hip/hip_runtime.h>

#define N_NODES 50000
#define N_EDGES 800000
#define NFEAT   512
#define NHID    256
#define NCLASS  64

#define MTILES     ((N_NODES + 63) / 64)      // 782

// ---- bucketed CSR build params ----
#define NBUCK      196                        // ceil(50000/256), bucket = dst>>8
#define BCAP       5632                       // expected 4096 +- 64; +24 sigma margin
#define BIN_CHUNK  4096
#define BIN_BLOCKS ((N_EDGES + BIN_CHUNK - 1) / BIN_CHUNK)   // 196 per list
#define PREP_BLOCKS (2 * BIN_BLOCKS + 32 + 4)                // binscatter + casts
#define FUSE_BLOCKS (2 * NBUCK + MTILES)                     // bucket_csr + gemm1

typedef short short8  __attribute__((ext_vector_type(8)));
typedef float floatx4 __attribute__((ext_vector_type(4)));
typedef float floatx2 __attribute__((ext_vector_type(2)));

__device__ inline short f2bf(float f) {
    unsigned u = __builtin_bit_cast(unsigned, f);
    u += 0x7FFF + ((u >> 16) & 1);   // round-to-nearest-even
    return (short)(u >> 16);
}
__device__ inline float bf2f(short v) {
    unsigned u = ((unsigned)(unsigned short)v) << 16;
    return __builtin_bit_cast(float, u);
}
// packed edge: low 16 bits = src node id (50000 < 65536), high 16 = bf16 weight
__device__ inline int pack_edge(int src, float w) {
    return (src & 0xFFFF) | ((int)(unsigned short)f2bf(w) << 16);
}

// ---- fp8 e4m3fn (OCP) helpers: HW cvt on gfx950, bit-manip fallback ----
#if defined(__has_builtin)
#if __has_builtin(__builtin_amdgcn_cvt_pk_f32_fp8) && __has_builtin(__builtin_amdgcn_cvt_pk_fp8_f32)
#define HAVE_HW_FP8 1
#endif
#endif

__device__ inline unsigned char f2fp8(float f) {
#ifdef HAVE_HW_FP8
    return (unsigned char)(__builtin_amdgcn_cvt_pk_fp8_f32(f, f, 0, false) & 0xFF);
#else
    unsigned u = __builtin_bit_cast(unsigned, f);
    unsigned s = (u >> 31) << 7;
    float af = fabsf(f);
    if (!(af >= 0.0009765625f)) {
        int q = (int)(af * 512.f + 0.5f);
        if (q > 7) q = 7;
        return (unsigned char)(s | q);
    }
    if (af > 448.f) return (unsigned char)(s | 0x7E);
    int ex; float mf = frexpf(af, &ex);
    int E = ex - 1;
    if (E < -6) {
        int q = (int)(af * 512.f + 0.5f);
        if (q > 7) q = 7;
        return (unsigned char)(s | q);
    }
    int m = (int)((2.f * mf - 1.f) * 8.f + 0.5f);
    if (m == 8) { m = 0; ++E; }
    if (E > 8) return (unsigned char)(s | 0x7E);
    return (unsigned char)(s | ((E + 7) << 3) | m);
#endif
}

__device__ inline void fp8x8_to_f32(uint2 v, float* o) {
#ifdef HAVE_HW_FP8
    floatx2 f0 = __builtin_amdgcn_cvt_pk_f32_fp8((int)v.x, false);
    floatx2 f1 = __builtin_amdgcn_cvt_pk_f32_fp8((int)v.x, true);
    floatx2 f2 = __builtin_amdgcn_cvt_pk_f32_fp8((int)v.y, false);
    floatx2 f3 = __builtin_amdgcn_cvt_pk_f32_fp8((int)v.y, true);
    o[0] = f0[0]; o[1] = f0[1]; o[2] = f1[0]; o[3] = f1[1];
    o[4] = f2[0]; o[5] = f2[1]; o[6] = f3[0]; o[7] = f3[1];
#else
    unsigned w[2] = {v.x, v.y};
    #pragma unroll
    for (int k = 0; k < 8; ++k) {
        unsigned char b = (w[k >> 2] >> ((k & 3) * 8)) & 0xFF;
        int sg = b >> 7, e = (b >> 3) & 15, m = b & 7;
        float val = e ? ldexpf(1.f + m * 0.125f, e - 7) : ldexpf(m * 0.125f, -6);
        o[k] = sg ? -val : val;
    }
#endif
}

// async global->LDS 16B: linear LDS dest (base + lane*16), per-lane global src
typedef __attribute__((address_space(3))) void       lds_void;
typedef __attribute__((address_space(1))) const void glb_void;
__device__ inline void gload_lds16(const void* g, void* l) {
    __builtin_amdgcn_global_load_lds((glb_void*)g, (lds_void*)l, 16, 0, 0);
}

// ---------------- prep: binscatter (both lists) + both weight casts, one dispatch ----
__global__ __launch_bounds__(256) void prep_kernel(
    const int* __restrict__ es0, const int* __restrict__ ed0, const float* __restrict__ ew0,
    int* __restrict__ cur0, int2* __restrict__ bin0,
    const int* __restrict__ es1, const int* __restrict__ ed1, const float* __restrict__ ew1,
    int* __restrict__ cur1, int2* __restrict__ bin1,
    const float* __restrict__ W1, short* __restrict__ Wt,
    const float* __restrict__ W2, short* __restrict__ W2t) {
    __shared__ union {
        int   hist[NBUCK];
        short tile[64][72];
    } sm;
    const int blk = blockIdx.x;
    const int t   = threadIdx.x;

    if (blk < 2 * BIN_BLOCKS) {
        // ---- binscatter ----
        const int list = blk >= BIN_BLOCKS;
        const int cb   = blk - list * BIN_BLOCKS;
        const int*   es  = list ? es1 : es0;
        const int*   ed  = list ? ed1 : ed0;
        const float* ew  = list ? ew1 : ew0;
        int*         cur = list ? cur1 : cur0;
        int2*        bin = list ? bin1 : bin0;

        const int e0 = cb * BIN_CHUNK;
        const int e1 = min(e0 + BIN_CHUNK, N_EDGES);

        if (t < NBUCK) sm.hist[t] = 0;
        __syncthreads();
        for (int e = e0 + t; e < e1; e += 256)
            atomicAdd(&sm.hist[ed[e] >> 8], 1);
        __syncthreads();
        if (t < NBUCK) sm.hist[t] = atomicAdd(&cur[t], sm.hist[t]);
        __syncthreads();
        for (int e = e0 + t; e < e1; e += 256) {
            int d = ed[e];
            int b = d >> 8;
            int p = atomicAdd(&sm.hist[b], 1);
            if (p < BCAP) {
                int2 v; v.x = pack_edge(es[e], ew[e]); v.y = d;
                bin[(size_t)b * BCAP + p] = v;
            }
        }
    } else if (blk < 2 * BIN_BLOCKS + 32) {
        // ---- cast W1 -> Wt [256x512] bf16 (transposed) ----
        const int cb = blk - 2 * BIN_BLOCKS;
        const int k0 = (cb >> 2) << 6;
        const int n0 = (cb & 3) << 6;
        {
            int kr = t >> 2, ng = (t & 3) << 4;
            const float* src = W1 + (size_t)(k0 + kr) * NHID + n0 + ng;
            float4 v0 = ((const float4*)src)[0], v1 = ((const float4*)src)[1];
            float4 v2 = ((const float4*)src)[2], v3 = ((const float4*)src)[3];
            short* d = &sm.tile[kr][ng];
            d[0]=f2bf(v0.x); d[1]=f2bf(v0.y); d[2]=f2bf(v0.z); d[3]=f2bf(v0.w);
            d[4]=f2bf(v1.x); d[5]=f2bf(v1.y); d[6]=f2bf(v1.z); d[7]=f2bf(v1.w);
            d[8]=f2bf(v2.x); d[9]=f2bf(v2.y); d[10]=f2bf(v2.z); d[11]=f2bf(v2.w);
            d[12]=f2bf(v3.x); d[13]=f2bf(v3.y); d[14]=f2bf(v3.z); d[15]=f2bf(v3.w);
        }
        __syncthreads();
        {
            int nr = t >> 2, kg = (t & 3) << 4;
            short8 o0, o1;
            #pragma unroll
            for (int j = 0; j < 8; ++j) { o0[j] = sm.tile[kg + j][nr]; o1[j] = sm.tile[kg + 8 + j][nr]; }
            short* d = Wt + (size_t)(n0 + nr) * NFEAT + k0 + kg;
            *(short8*)d = o0;
            *(short8*)(d + 8) = o1;
        }
    } else {
        // ---- cast W2 -> W2t [64x256] bf16 (transposed) ----
        const int cb = blk - 2 * BIN_BLOCKS - 32;
        const int k0 = cb << 6;
        {
            int kr = t >> 2, ng = (t & 3) << 4;
            const float* src = W2 + (size_t)(k0 + kr) * NCLASS + ng;
            float4 v0 = ((const float4*)src)[0], v1 = ((const float4*)src)[1];
            float4 v2 = ((const float4*)src)[2], v3 = ((const float4*)src)[3];
            short* d = &sm.tile[kr][ng];
            d[0]=f2bf(v0.x); d[1]=f2bf(v0.y); d[2]=f2bf(v0.z); d[3]=f2bf(v0.w);
            d[4]=f2bf(v1.x); d[5]=f2bf(v1.y); d[6]=f2bf(v1.z); d[7]=f2bf(v1.w);
            d[8]=f2bf(v2.x); d[9]=f2bf(v2.y); d[10]=f2bf(v2.z); d[11]=f2bf(v2.w);
            d[12]=f2bf(v3.x); d[13]=f2bf(v3.y); d[14]=f2bf(v3.z); d[15]=f2bf(v3.w);
        }
        __syncthreads();
        {
            int nr = t >> 2, kg = (t & 3) << 4;
            short8 o0, o1;
            #pragma unroll
            for (int j = 0; j < 8; ++j) { o0[j] = sm.tile[kg + j][nr]; o1[j] = sm.tile[kg + 8 + j][nr]; }
            short* d = W2t + (size_t)nr * NHID + k0 + kg;
            *(short8*)d = o0;
            *(short8*)(d + 8) = o1;
        }
    }
}

// ------- FUSED: bucket_csr (blocks [0,392)) + gemm1 (blocks [392,392+782)) ---------
// Round-6 lesson: the 80KB dbuf union capped occupancy at 2 blocks/CU and killed it.
// This version uses the SINGLE-BUFFER gemm1 (As 8KB + Bs 32KB = 40KB union -> 4
// blocks/CU, gemm1's standalone regime) while keeping the csr/gemm1 overlap.
__global__ __launch_bounds__(256) void csr_gemm1_kernel(
    const int* __restrict__ cur0, const int2* __restrict__ bin0,
    int* __restrict__ deg0, int* __restrict__ base0, int* __restrict__ edge0,
    const int* __restrict__ cur1, const int2* __restrict__ bin1,
    int* __restrict__ deg1, int* __restrict__ base1, int* __restrict__ edge1,
    const float* __restrict__ x, const short* __restrict__ Wt,
    unsigned char* __restrict__ h0f) {
    __shared__ union {
        struct { short As[64 * 64]; short Bs[256 * 64]; } g;   // 40 KB (gemm1)
        struct { int dh[256]; int sc[256]; int pc[256]; } c;   // 3 KB  (csr)
    } sm;
    const int tid = threadIdx.x;

    if (blockIdx.x < 2 * NBUCK) {
        // ================= bucket_csr (inlined 196-bucket prefix scan) =============
        const int list = blockIdx.x >= NBUCK;
        const int b    = blockIdx.x - list * NBUCK;
        const int*  cur  = list ? cur1  : cur0;
        const int2* bin  = (list ? bin1 : bin0) + (size_t)b * BCAP;
        int*        deg  = list ? deg1  : deg0;
        int*        base = list ? base1 : base0;
        int*        edge = list ? edge1 : edge0;
        const int t = tid;

        sm.c.pc[t] = (t < NBUCK) ? min(cur[t], BCAP) : 0;
        sm.c.dh[t] = 0;
        __syncthreads();
        for (int off = 1; off < 256; off <<= 1) {
            int a = (t >= off) ? sm.c.pc[t - off] : 0;
            __syncthreads();
            sm.c.pc[t] += a;
            __syncthreads();
        }
        const int gbase = b ? sm.c.pc[b - 1] : 0;
        const int len   = min(cur[b], BCAP);
        const int n0    = b << 8;

        for (int i = t; i < len; i += 256)
            atomicAdd(&sm.c.dh[bin[i].y & 255], 1);
        __syncthreads();
        int v = sm.c.dh[t];
        sm.c.sc[t] = v;
        __syncthreads();
        for (int off = 1; off < 256; off <<= 1) {
            int a = (t >= off) ? sm.c.sc[t - off] : 0;
            __syncthreads();
            sm.c.sc[t] += a;
            __syncthreads();
        }
        int excl = sm.c.sc[t] - v;
        int node = n0 + t;
        if (node < N_NODES) { deg[node] = v; base[node] = gbase + excl; }
        sm.c.dh[t] = gbase + excl;
        __syncthreads();
        for (int i = t; i < len; i += 256) {
            int2 ev = bin[i];
            int p = atomicAdd(&sm.c.dh[ev.y & 255], 1);
            edge[p] = ev.x;
        }
        return;
    }

    // ====== gemm1: h0 = fp8(x @ W1), BK=64, swizzled LDS, single-buffer ===========
    const int tile = blockIdx.x - 2 * NBUCK;
    const int wave = tid >> 6, lane = tid & 63;
    const int mlo  = lane & 15, q = lane >> 4;
    const int m0   = tile * 64;

    const int ar = tid >> 2;
    const int cp = (tid & 3) * 2;
    int arow = m0 + ar; if (arow >= N_NODES) arow = N_NODES - 1;
    const float* aptr = x + (size_t)arow * NFEAT + cp * 8;

    const int brl = lane >> 3;
    const int bsl = lane & 7;

    floatx4 acc[4][4] = {};

    for (int kc = 0; kc < NFEAT; kc += 64) {
        // issue async B loads (each wave fills exactly the 64 rows it consumes)
        #pragma unroll
        for (int i = 0; i < 8; ++i) {
            int r  = wave * 64 + i * 8 + brl;
            int s2 = bsl ^ (r & 7);
            gload_lds16(Wt + (size_t)r * NFEAT + kc + s2 * 8,
                        &sm.g.Bs[(wave * 64 + i * 8) * 64]);
        }
        // A: 16 fp32 -> bf16 -> 2 swizzled ds_write_b128
        float4 a0 = *(const float4*)(aptr + kc);
        float4 a1 = *(const float4*)(aptr + kc + 4);
        float4 a2 = *(const float4*)(aptr + kc + 8);
        float4 a3 = *(const float4*)(aptr + kc + 12);
        short8 p0, p1;
        p0[0]=f2bf(a0.x); p0[1]=f2bf(a0.y); p0[2]=f2bf(a0.z); p0[3]=f2bf(a0.w);
        p0[4]=f2bf(a1.x); p0[5]=f2bf(a1.y); p0[6]=f2bf(a1.z); p0[7]=f2bf(a1.w);
        p1[0]=f2bf(a2.x); p1[1]=f2bf(a2.y); p1[2]=f2bf(a2.z); p1[3]=f2bf(a2.w);
        p1[4]=f2bf(a3.x); p1[5]=f2bf(a3.y); p1[6]=f2bf(a3.z); p1[7]=f2bf(a3.w);
        *(short8*)&sm.g.As[ar * 64 + ((cp     ) ^ (ar & 7)) * 8] = p0;
        *(short8*)&sm.g.As[ar * 64 + ((cp + 1) ^ (ar & 7)) * 8] = p1;
        __syncthreads();   // drains vmcnt (B) + lgkmcnt (A)

        #pragma unroll
        for (int h = 0; h < 2; ++h) {
            short8 afv[4], bfv[4];
            #pragma unroll
            for (int t2 = 0; t2 < 4; ++t2) {
                int r = t2 * 16 + mlo;
                afv[t2] = *(const short8*)&sm.g.As[r * 64 + ((h * 4 + q) ^ (r & 7)) * 8];
            }
            #pragma unroll
            for (int u = 0; u < 4; ++u) {
                int r = wave * 64 + u * 16 + mlo;
                bfv[u] = *(const short8*)&sm.g.Bs[r * 64 + ((h * 4 + q) ^ (r & 7)) * 8];
            }
            #pragma unroll
            for (int t2 = 0; t2 < 4; ++t2)
                #pragma unroll
                for (int u = 0; u < 4; ++u)
                    acc[t2][u] = __builtin_amdgcn_mfma_f32_16x16x32_bf16(afv[t2], bfv[u], acc[t2][u], 0, 0, 0);
        }
        __syncthreads();
    }

    #pragma unroll
    for (int t2 = 0; t2 < 4; ++t2) {
        #pragma unroll
        for (int r = 0; r < 4; ++r) {
            int row = m0 + t2 * 16 + q * 4 + r;
            if (row < N_NODES) {
                #pragma unroll
                for (int u = 0; u < 4; ++u)
                    h0f[(size_t)row * NHID + wave * 64 + u * 16 + mlo] = f2fp8(acc[t2][u][r]);
            }
        }
    }
}

// ---------------- SpMM1 pull (fp8, d=256): XCD feature-split, 4 slots, depth-3 ------
__global__ __launch_bounds__(256) void spmm1_pull_kernel(const int* __restrict__ base,
                                                         const int* __restrict__ deg,
                                                         const int* __restrict__ edge_s,
                                                         const unsigned char* __restrict__ h0f,
                                                         short* __restrict__ agg0b) {
    const int g    = blockIdx.x;
    const int r7   = g & 7;
    const int half = r7 >> 2;                       // 0/1 feature half
    const int nb   = (g >> 3) * 4 + (r7 & 3);       // node-block 0..12499
    const int node = nb * 4 + (threadIdx.x >> 6);
    const int lane = threadIdx.x & 63;
    const int slot = lane >> 4;                     // 4 slots, stride 4
    const int c    = lane & 15;
    const int fof  = half * 128 + c * 8;            // feature offset (fp8: 1 B/elem)
    const int start = base[node];
    const int len   = deg[node];

    float acc[8] = {0.f,0.f,0.f,0.f,0.f,0.f,0.f,0.f};

    int eA = 0, eB = 0, eC = 0, eD = 0;
    uint2 z = {0u, 0u};
    uint2 hA = z, hB = z, hC = z;
    if (slot      < len) eA = edge_s[start + slot];
    if (slot + 4  < len) eB = edge_s[start + slot + 4];
    if (slot + 8  < len) eC = edge_s[start + slot + 8];
    if (slot + 12 < len) eD = edge_s[start + slot + 12];
    if (slot      < len) hA = *(const uint2*)(h0f + (size_t)(eA & 0xFFFF) * NHID + fof);
    if (slot + 4  < len) hB = *(const uint2*)(h0f + (size_t)(eB & 0xFFFF) * NHID + fof);
    if (slot + 8  < len) hC = *(const uint2*)(h0f + (size_t)(eC & 0xFFFF) * NHID + fof);

    int jr = slot + 12;   // next row index to issue
    int je = slot + 16;   // next edge index to fetch
    for (int j = slot; j < len; j += 4) {
        float wt = bf2f((short)((unsigned)eA >> 16));
        float f[8];
        fp8x8_to_f32(hA, f);
        #pragma unroll
        for (int k = 0; k < 8; ++k) acc[k] += wt * f[k];
        eA = eB; hA = hB;
        eB = eC; hB = hC;
        eC = eD;
        if (jr < len) hC = *(const uint2*)(h0f + (size_t)(eC & 0xFFFF) * NHID + fof);
        if (je < len) eD = edge_s[start + je];
        jr += 4; je += 4;
    }

    #pragma unroll
    for (int k = 0; k < 8; ++k) {
        acc[k] += __shfl_xor(acc[k], 16);
        acc[k] += __shfl_xor(acc[k], 32);
    }
    if (slot == 0) {
        short8 ob;
        #pragma unroll
        for (int k = 0; k < 8; ++k) ob[k] = f2bf(acc[k]);
        *(short8*)(agg0b + (size_t)node * NHID + fof) = ob;
    }
}

// ---------------- GEMM2: h2 = bf16(relu(agg0b + b1) @ W2), BK=64, swizzled LDS ------
__global__ __launch_bounds__(256) void gemm2_mfma_kernel(const short* __restrict__ agg0b,
                                                         const float* __restrict__ b1,
                                                         const short* __restrict__ W2t,
                                                         short* __restrict__ h2b) {
    __shared__ short Bs[64 * 256];   // 32 KB [n][k=256] swizzled (chunk ^= row&7)
    __shared__ short As[64 * 64];    // 8 KB  [m][k] swizzled
    const int tid  = threadIdx.x;
    const int wave = tid >> 6, lane = tid & 63;
    const int mlo  = lane & 15, q = lane >> 4;
    const int m0   = blockIdx.x * 64;

    {   // stage full W2t [64x256] once, swizzled
        int n = tid >> 2;
        #pragma unroll
        for (int j = 0; j < 8; ++j) {
            int c  = (tid & 3) * 8 + j;              // chunk 0..31
            int s2 = c ^ (n & 7);
            *(short8*)&Bs[n * 256 + s2 * 8] =
                *(const short8*)(W2t + (size_t)n * NHID + c * 8);
        }
    }

    const int ar = tid >> 2;
    const int cp = (tid & 3) * 2;
    int arow = m0 + ar; if (arow >= N_NODES) arow = N_NODES - 1;
    const short* aptr = agg0b + (size_t)arow * NHID + cp * 8;

    floatx4 acc[4] = {};   // [ntile]

    for (int kc = 0; kc < NHID; kc += 64) {
        short8 s0 = *(const short8*)(aptr + kc);
        short8 s1 = *(const short8*)(aptr + kc + 8);
        float4 c0 = *(const float4*)(b1 + kc + cp * 8);
        float4 c1 = *(const float4*)(b1 + kc + cp * 8 + 4);
        float4 c2 = *(const float4*)(b1 + kc + cp * 8 + 8);
        float4 c3 = *(const float4*)(b1 + kc + cp * 8 + 12);
        float v0 = bf2f(s0[0]) + c0.x, v1 = bf2f(s0[1]) + c0.y;
        float v2 = bf2f(s0[2]) + c0.z, v3 = bf2f(s0[3]) + c0.w;
        float v4 = bf2f(s0[4]) + c1.x, v5 = bf2f(s0[5]) + c1.y;
        float v6 = bf2f(s0[6]) + c1.z, v7 = bf2f(s0[7]) + c1.w;
        float v8 = bf2f(s1[0]) + c2.x, v9 = bf2f(s1[1]) + c2.y;
        float vA = bf2f(s1[2]) + c2.z, vB = bf2f(s1[3]) + c2.w;
        float vC = bf2f(s1[4]) + c3.x, vD = bf2f(s1[5]) + c3.y;
        float vE = bf2f(s1[6]) + c3.z, vF = bf2f(s1[7]) + c3.w;
        short8 p0, p1;
        p0[0]=f2bf(v0>0.f?v0:0.f); p0[1]=f2bf(v1>0.f?v1:0.f); p0[2]=f2bf(v2>0.f?v2:0.f); p0[3]=f2bf(v3>0.f?v3:0.f);
        p0[4]=f2bf(v4>0.f?v4:0.f); p0[5]=f2bf(v5>0.f?v5:0.f); p0[6]=f2bf(v6>0.f?v6:0.f); p0[7]=f2bf(v7>0.f?v7:0.f);
        p1[0]=f2bf(v8>0.f?v8:0.f); p1[1]=f2bf(v9>0.f?v9:0.f); p1[2]=f2bf(vA>0.f?vA:0.f); p1[3]=f2bf(vB>0.f?vB:0.f);
        p1[4]=f2bf(vC>0.f?vC:0.f); p1[5]=f2bf(vD>0.f?vD:0.f); p1[6]=f2bf(vE>0.f?vE:0.f); p1[7]=f2bf(vF>0.f?vF:0.f);
        *(short8*)&As[ar * 64 + ((cp     ) ^ (ar & 7)) * 8] = p0;
        *(short8*)&As[ar * 64 + ((cp + 1) ^ (ar & 7)) * 8] = p1;
        __syncthreads();

        short8 afv[2];
        {
            int r = wave * 16 + mlo;
            afv[0] = *(const short8*)&As[r * 64 + ((    q) ^ (r & 7)) * 8];
            afv[1] = *(const short8*)&As[r * 64 + ((4 + q) ^ (r & 7)) * 8];
        }
        #pragma unroll
        for (int u = 0; u < 4; ++u) {
            int r = u * 16 + mlo;
            #pragma unroll
            for (int h = 0; h < 2; ++h) {
                int ch = (kc >> 3) + h * 4 + q;
                short8 bv = *(const short8*)&Bs[r * 256 + (ch ^ (r & 7)) * 8];
                acc[u] = __builtin_amdgcn_mfma_f32_16x16x32_bf16(afv[h], bv, acc[u], 0, 0, 0);
            }
        }
        __syncthreads();
    }

    #pragma unroll
    for (int r = 0; r < 4; ++r) {
        int row = m0 + wave * 16 + q * 4 + r;
        if (row < N_NODES) {
            #pragma unroll
            for (int u = 0; u < 4; ++u)
                h2b[(size_t)row * NCLASS + u * 16 + mlo] = f2bf(acc[u][r]);
        }
    }
}

// ---------------- Fused SpMM2 + bias + log_softmax (d=64) ----------------
__global__ __launch_bounds__(256) void spmm2_lsm_kernel(const int* __restrict__ base,
                                                        const int* __restrict__ deg,
                                                        const int* __restrict__ edge_s,
                                                        const short* __restrict__ h2b,
                                                        const float* __restrict__ b2,
                                                        float* __restrict__ out) {
    const int node = blockIdx.x * 4 + (threadIdx.x >> 6);
    const int lane = threadIdx.x & 63;
    const int slot = lane >> 3;
    const int f    = lane & 7;          // feats f*8..f*8+7
    const int start = base[node];
    const int len   = deg[node];

    float acc[8] = {0.f,0.f,0.f,0.f,0.f,0.f,0.f,0.f};
    int j = slot;
    int e = 0;
    short8 hv = {0,0,0,0,0,0,0,0};
    if (j < len) {
        e  = edge_s[start + j];
        hv = *(const short8*)(h2b + (size_t)(e & 0xFFFF) * NCLASS + f * 8);
    }
    while (j < len) {
        float wt = bf2f((short)((unsigned)e >> 16));
        int jn = j + 8;
        int en = e; short8 hn = hv;
        if (jn < len) {
            en = edge_s[start + jn];
            hn = *(const short8*)(h2b + (size_t)(en & 0xFFFF) * NCLASS + f * 8);
        }
        #pragma unroll
        for (int k = 0; k < 8; ++k) acc[k] += wt * bf2f(hv[k]);
        e = en; hv = hn; j = jn;
    }
    #pragma unroll
    for (int k = 0; k < 8; ++k) {
        acc[k] += __shfl_xor(acc[k], 8);
        acc[k] += __shfl_xor(acc[k], 16);
        acc[k] += __shfl_xor(acc[k], 32);
    }
    float4 c0 = *(const float4*)(b2 + f * 8);
    float4 c1 = *(const float4*)(b2 + f * 8 + 4);
    float v[8];
    v[0] = acc[0] + c0.x; v[1] = acc[1] + c0.y; v[2] = acc[2] + c0.z; v[3] = acc[3] + c0.w;
    v[4] = acc[4] + c1.x; v[5] = acc[5] + c1.y; v[6] = acc[6] + c1.z; v[7] = acc[7] + c1.w;
    float m = v[0];
    #pragma unroll
    for (int k = 1; k < 8; ++k) m = fmaxf(m, v[k]);
    m = fmaxf(m, __shfl_xor(m, 1));
    m = fmaxf(m, __shfl_xor(m, 2));
    m = fmaxf(m, __shfl_xor(m, 4));
    float s = 0.f;
    #pragma unroll
    for (int k = 0; k < 8; ++k) s += __expf(v[k] - m);
    s += __shfl_xor(s, 1);
    s += __shfl_xor(s, 2);
    s += __shfl_xor(s, 4);
    float ls = m + __logf(s);
    if (slot == 0) {
        float4 o0 = {v[0] - ls, v[1] - ls, v[2] - ls, v[3] - ls};
        float4 o1 = {v[4] - ls, v[5] - ls, v[6] - ls, v[7] - ls};
        float* p = out + (size_t)node * NCLASS + f * 8;
        *(float4*)p = o0;
        *(float4*)(p + 4) = o1;
    }
}

extern "C" void kernel_launch(void* const* d_in, const int* in_sizes, int n_in,
                              void* d_out, int out_size, void* d_ws, size_t ws_size,
                              hipStream_t stream) {
    const float* x   = (const float*)d_in[0];
    const int*   es0 = (const int*)  d_in[1];
    const int*   ed0 = (const int*)  d_in[2];
    const float* ew0 = (const float*)d_in[3];
    const int*   es1 = (const int*)  d_in[4];
    const int*   ed1 = (const int*)  d_in[5];
    const float* ew1 = (const float*)d_in[6];
    const float* W1  = (const float*)d_in[7];
    const float* b1  = (const float*)d_in[8];
    const float* W2  = (const float*)d_in[9];
    const float* b2  = (const float*)d_in[10];
    float* out = (float*)d_out;

    // ws layout:
    //   [0, 12.8MB):      h0f fp8 [50000x256]; later h2b bf16 [50000x64] at [0,6.4)
    //   [25.6, 43.3MB):   bin0, bin1 (196 buckets x 5632 x 8B each)  [build-only]
    //   [44.0, 47.7MB):   CSR1 (deg1/base1/edge1) + bucket cursors
    //   [51.2, 76.8MB):   agg0b bf16 [50000x256]
    char* ws = (char*)d_ws;
    const size_t SZ_H0 = (size_t)N_NODES * NHID * sizeof(short);     // 25.6 MB (layout anchor)
    const size_t SZ_BIN = (size_t)NBUCK * BCAP * sizeof(int2);       // 8.83 MB
    unsigned char* h0f = (unsigned char*)ws;
    short* h2b   = (short*)ws;
    short* agg0b = (short*)(ws + (size_t)N_NODES * NHID * sizeof(float));   // 51.2MB

    int2* bin0 = (int2*)(ws + SZ_H0);
    int2* bin1 = (int2*)(ws + SZ_H0 + SZ_BIN);

    char* c1 = ws + 44000000;
    int* deg1  = (int*)c1;
    int* base1 = deg1 + N_NODES;
    int* edge1 = base1 + N_NODES;
    int* cur0  = edge1 + N_EDGES;
    int* cur1  = cur0 + 256;

    // d_out scratch (12.8 MB; CSR0 dead after spmm1; Wt/W2t dead after gemms;
    // final fused spmm2+logsoftmax overwrites all of d_out):
    int*   deg0  = (int*)d_out;
    int*   base0 = deg0 + N_NODES;
    int*   edge0 = base0 + N_NODES;
    short* Wt    = (short*)((char*)d_out + (8u << 20));
    short* W2t   = (short*)((char*)d_out + (9u << 20));

    // ---- build both CSRs + weight casts (fused prep) ----
    hipMemsetAsync(cur0, 0, 512 * sizeof(int), stream);   // cur0 + cur1
    prep_kernel<<<PREP_BLOCKS, 256, 0, stream>>>(es0, ed0, ew0, cur0, bin0,
                                                 es1, ed1, ew1, cur1, bin1,
                                                 W1, Wt, W2, W2t);

    // ---- fused: CSR finalize (independent) + layer-1 GEMM (40KB union) ----
    csr_gemm1_kernel<<<FUSE_BLOCKS, 256, 0, stream>>>(cur0, bin0, deg0, base0, edge0,
                                                      cur1, bin1, deg1, base1, edge1,
                                                      x, Wt, h0f);

    // ---- layer 1 aggregation ----
    spmm1_pull_kernel<<<2 * (N_NODES / 4), 256, 0, stream>>>(base0, deg0, edge0, h0f, agg0b);

    // ---- layer 2 (spmm2 fused with bias + log_softmax, writes out directly) ----
    gemm2_mfma_kernel<<<MTILES, 256, 0, stream>>>(agg0b, b1, W2t, h2b);
    spmm2_lsm_kernel<<<N_NODES / 4, 256, 0, stream>>>(base1, deg1, edge1, h2b, b2, out);
}